// Round 1
// 1438.047 us; speedup vs baseline: 1.1750x; 1.1750x over previous
//
#include <hip/hip_runtime.h>

typedef unsigned short u16;
typedef unsigned int   u32;
typedef __attribute__((ext_vector_type(8))) short bf16x8;
typedef __attribute__((ext_vector_type(4))) float f32x4;
typedef __attribute__((ext_vector_type(16))) float f32x16;

static __device__ __forceinline__ float bf2f(u16 u) {
  union { u32 i; float f; } v; v.i = ((u32)u) << 16; return v.f;
}
static __device__ __forceinline__ u16 f2bf(float f) {
  union { float f; u32 i; } v; v.f = f;
  u32 u = v.i;
  u32 r = (u + 0x7FFFu + ((u >> 16) & 1u)) >> 16;  // RNE
  return (u16)r;
}

// ---------------- f32 -> bf16 conversion, 8 elems/thread ----------------
__global__ __launch_bounds__(256) void cvt_bf16(const float* __restrict__ in,
                                                u16* __restrict__ out, long n) {
  long i = ((long)blockIdx.x * 256 + threadIdx.x) * 8;
  if (i >= n) return;
  float4 a = *(const float4*)(in + i);
  float4 b = *(const float4*)(in + i + 4);
  uint4 o;
  o.x = (u32)f2bf(a.x) | ((u32)f2bf(a.y) << 16);
  o.y = (u32)f2bf(a.z) | ((u32)f2bf(a.w) << 16);
  o.z = (u32)f2bf(b.x) | ((u32)f2bf(b.y) << 16);
  o.w = (u32)f2bf(b.z) | ((u32)f2bf(b.w) << 16);
  *(uint4*)(out + i) = o;
}

// ---------------- GEMM: C[r][c] = sum_k A[r][k] * W[c][k]  (nn.Linear) ----
// A: Mrows x 512 bf16 row-major, W: 512 x 512 bf16 row-major.
// Tile 128x128, BK=32, 4 waves (2x2 of 64x64), MFMA 16x16x32 bf16.
// MODE 0: store bf16 C. MODE 1: store fp32 C + bias[col] + resid[r][c].
#define LDA 40  // padded LDS row stride (elems): stride 80B -> <=2-way bank conflicts
template <int MODE>
__global__ __launch_bounds__(256) void gemm_bt(
    const u16* __restrict__ A, const u16* __restrict__ W,
    u16* __restrict__ Cb, float* __restrict__ Cf,
    const float* __restrict__ bias, const float* __restrict__ resid) {
  __shared__ __align__(16) u16 As[128 * LDA];
  __shared__ __align__(16) u16 Bs[128 * LDA];
  const int t = threadIdx.x;
  const int lane = t & 63, wave = t >> 6;
  const int wy = wave >> 1, wx = wave & 1;
  const int quad = lane >> 4, l15 = lane & 15;
  const long arow0 = (long)blockIdx.x * 128;
  const int  brow0 = blockIdx.y * 128;

  f32x4 acc[4][4];
#pragma unroll
  for (int i = 0; i < 4; i++)
#pragma unroll
    for (int j = 0; j < 4; j++) acc[i][j] = (f32x4){0.f, 0.f, 0.f, 0.f};

  for (int k0 = 0; k0 < 512; k0 += 32) {
    // stage 128x32 A-tile and B-tile (512 x 16B chunks each)
    for (int c = t; c < 512; c += 256) {
      const int row = c >> 2, seg = c & 3;
      uint4 va = *(const uint4*)(A + (arow0 + row) * 512 + k0 + seg * 8);
      uint4 vb = *(const uint4*)(W + (long)(brow0 + row) * 512 + k0 + seg * 8);
      *(uint4*)(As + row * LDA + seg * 8) = va;
      *(uint4*)(Bs + row * LDA + seg * 8) = vb;
    }
    __syncthreads();
    bf16x8 af[4], bfr[4];
#pragma unroll
    for (int mt = 0; mt < 4; mt++)
      af[mt] = *(const bf16x8*)(As + (wy * 64 + mt * 16 + l15) * LDA + quad * 8);
#pragma unroll
    for (int nt = 0; nt < 4; nt++)
      bfr[nt] = *(const bf16x8*)(Bs + (wx * 64 + nt * 16 + l15) * LDA + quad * 8);
#pragma unroll
    for (int mt = 0; mt < 4; mt++)
#pragma unroll
      for (int nt = 0; nt < 4; nt++)
        acc[mt][nt] = __builtin_amdgcn_mfma_f32_16x16x32_bf16(af[mt], bfr[nt],
                                                              acc[mt][nt], 0, 0, 0);
    __syncthreads();
  }

#pragma unroll
  for (int mt = 0; mt < 4; mt++) {
#pragma unroll
    for (int r = 0; r < 4; r++) {
      const long row = arow0 + wy * 64 + mt * 16 + quad * 4 + r;
#pragma unroll
      for (int nt = 0; nt < 4; nt++) {
        const int col = brow0 + wx * 64 + nt * 16 + l15;
        const float v = acc[mt][nt][r];
        if (MODE == 0) {
          Cb[row * 512 + col] = f2bf(v);
        } else {
          Cf[row * 512 + col] = v + bias[col] + resid[row * 512 + col];
        }
      }
    }
  }
}

// ---------------- attention (MFMA): one block per sample n ----------------
// 4 waves; wave w does heads w and w+4. Per (n,h), one wave:
//   S^T = K . Q^T  via v_mfma_f32_32x32x16_bf16  (lane owns query col i=lane&31)
//   A-frag(K): K[j=lane&31][m=(lane>>5)*8+e]  -> 16B global load (no reuse, no LDS)
//   B-frag(Q): Q[i=lane&31][m=(lane>>5)*8+e]  -> 16B global load
//   C/D: col=lane&31, row=(reg&3)+8*(reg>>2)+4*(lane>>5)  [m74/m101 layout]
// Softmax per lane over j: own regs give j in {0-3,8-11,16}+4*hi; one
// shfl_xor(32) set supplies the other half. Rows/cols 17..31 are padding
// garbage and never used (row r of D depends only on row r of A).
// PV: ctx = P . V, A = packed p (registers), B = V from row-major LDS.
// K-step 1 feeds only j=16 explicitly (zeros elsewhere): exact, no overread.
__global__ __launch_bounds__(256) void attn(
    const u16* __restrict__ Q, const u16* __restrict__ K, const u16* __restrict__ V,
    const float* __restrict__ P, u16* __restrict__ CTX) {
  __shared__ __align__(16) u16 vs[17 * 512];
  __shared__ float Ps[17 * 17];
  const int t = threadIdx.x;
  const long base = (long)blockIdx.x * (17 * 512);
  for (int c = t; c < 1088; c += 256)
    ((uint4*)vs)[c] = *(const uint4*)(V + base + c * 8);
  for (int c = t; c < 289; c += 256) Ps[c] = P[c];
  __syncthreads();

  const int lane = t & 63, wave = t >> 6;
  const int l31 = lane & 31, hi = lane >> 5;
  const int i17 = l31 < 17 ? l31 : 16;  // clamp for P row (garbage lanes)

  for (int hh = 0; hh < 2; hh++) {
    const int h = wave + hh * 4;
    const u16* kbase = K + base + (long)l31 * 512 + h * 64 + hi * 8;
    const u16* qbase = Q + base + (long)l31 * 512 + h * 64 + hi * 8;

    // ---- QK^T: 4 k-steps of 16 over m=0..63 ----
    f32x16 acc;
#pragma unroll
    for (int r = 0; r < 16; r++) acc[r] = 0.f;
#pragma unroll
    for (int ks = 0; ks < 4; ks++) {
      bf16x8 ka = *(const bf16x8*)(kbase + ks * 16);
      bf16x8 qb = *(const bf16x8*)(qbase + ks * 16);
      acc = __builtin_amdgcn_mfma_f32_32x32x16_bf16(ka, qb, acc, 0, 0, 0);
    }

    // ---- scale + P bias on the 9 regs with j_own <= 16, then swap halves ----
    float tt[9], xx[9];
#pragma unroll
    for (int r = 0; r < 9; r++) {
      const int jown = (r & 3) + 8 * (r >> 2);  // 0..3, 8..11, 16
      int j = jown + 4 * hi;
      if (j > 16) j = 16;                        // only hi=1,r=8 (unused via cross)
      tt[r] = acc[r] * 0.125f + Ps[i17 * 17 + j];
    }
#pragma unroll
    for (int r = 0; r < 9; r++) xx[r] = __shfl_xor(tt[r], 32, 64);

    // ---- assemble s[0..16] (lane = query column i) ----
    float s[17];
#pragma unroll
    for (int r = 0; r < 4; r++) {
      s[r]      = hi ? xx[r] : tt[r];
      s[r + 4]  = hi ? tt[r] : xx[r];
      s[r + 8]  = hi ? xx[r + 4] : tt[r + 4];
      s[r + 12] = hi ? tt[r + 4] : xx[r + 4];
    }
    s[16] = hi ? xx[8] : tt[8];

    float mx = s[0];
#pragma unroll
    for (int j = 1; j < 17; j++) mx = fmaxf(mx, s[j]);
    float p[17], sum = 0.f;
#pragma unroll
    for (int j = 0; j < 17; j++) { p[j] = __expf(s[j] - mx); sum += p[j]; }
    const float inv = 1.f / sum;

    // ---- pack P row (A-frag): kstep0 k=0..15, kstep1 only k=16 live ----
    bf16x8 pa0, pa1;
#pragma unroll
    for (int e = 0; e < 8; e++) {
      const float v0 = (hi ? p[8 + e] : p[e]) * inv;
      pa0[e] = (short)f2bf(v0);
      pa1[e] = 0;
    }
    if (hi == 0) pa1[0] = (short)f2bf(p[16] * inv);

    // ---- PV: 2 column tiles of 32 ----
#pragma unroll
    for (int tile = 0; tile < 2; tile++) {
      const int c = h * 64 + tile * 32 + l31;
      bf16x8 vb0, vb1;
#pragma unroll
      for (int e = 0; e < 8; e++) {
        vb0[e] = (short)vs[(hi * 8 + e) * 512 + c];  // j = 0..15
        vb1[e] = 0;
      }
      if (hi == 0) vb1[0] = (short)vs[16 * 512 + c];  // j = 16

      f32x16 o;
#pragma unroll
      for (int r = 0; r < 16; r++) o[r] = 0.f;
      o = __builtin_amdgcn_mfma_f32_32x32x16_bf16(pa0, vb0, o, 0, 0, 0);
      o = __builtin_amdgcn_mfma_f32_32x32x16_bf16(pa1, vb1, o, 0, 0, 0);

      u16* cp = CTX + base + c;
#pragma unroll
      for (int r = 0; r < 16; r++) {
        const int i = (r & 3) + 8 * (r >> 2) + 4 * hi;
        if (i < 17) cp[(long)i * 512] = f2bf(o[r]);
      }
    }
  }
}

// ---------------- LayerNorm over M=512, one wave per row ------------------
__global__ __launch_bounds__(256) void ln_row(
    const float* __restrict__ X, const float* __restrict__ gamma,
    const float* __restrict__ beta, float* __restrict__ out) {
  const int lane = threadIdx.x & 63, wave = threadIdx.x >> 6;
  const long row = (long)blockIdx.x * 4 + wave;
  const float* xp = X + row * 512 + lane * 8;
  float4 a = *(const float4*)(xp);
  float4 b = *(const float4*)(xp + 4);
  float s  = a.x + a.y + a.z + a.w + b.x + b.y + b.z + b.w;
  float sq = a.x*a.x + a.y*a.y + a.z*a.z + a.w*a.w +
             b.x*b.x + b.y*b.y + b.z*b.z + b.w*b.w;
#pragma unroll
  for (int off = 1; off < 64; off <<= 1) {
    s  += __shfl_xor(s, off);
    sq += __shfl_xor(sq, off);
  }
  const float mean = s * (1.f / 512.f);
  const float var  = sq * (1.f / 512.f) - mean * mean;
  const float rstd = rsqrtf(var + 1e-5f);
  const float4 g0 = *(const float4*)(gamma + lane * 8);
  const float4 g1 = *(const float4*)(gamma + lane * 8 + 4);
  const float4 b0 = *(const float4*)(beta + lane * 8);
  const float4 b1 = *(const float4*)(beta + lane * 8 + 4);
  float4 o0, o1;
  o0.x = (a.x - mean) * rstd * g0.x + b0.x;
  o0.y = (a.y - mean) * rstd * g0.y + b0.y;
  o0.z = (a.z - mean) * rstd * g0.z + b0.z;
  o0.w = (a.w - mean) * rstd * g0.w + b0.w;
  o1.x = (b.x - mean) * rstd * g1.x + b1.x;
  o1.y = (b.y - mean) * rstd * g1.y + b1.y;
  o1.z = (b.z - mean) * rstd * g1.z + b1.z;
  o1.w = (b.w - mean) * rstd * g1.w + b1.w;
  float* op = out + row * 512 + lane * 8;
  *(float4*)op = o0;
  *(float4*)(op + 4) = o1;
}

extern "C" void kernel_launch(void* const* d_in, const int* in_sizes, int n_in,
                              void* d_out, int out_size, void* d_ws, size_t ws_size,
                              hipStream_t stream) {
  const float* x     = (const float*)d_in[0];
  const float* P     = (const float*)d_in[1];
  const float* Wq    = (const float*)d_in[2];
  const float* Wk    = (const float*)d_in[3];
  const float* Wv    = (const float*)d_in[4];
  const float* Wo    = (const float*)d_in[5];
  const float* bo    = (const float*)d_in[6];
  const float* gamma = (const float*)d_in[7];
  const float* beta  = (const float*)d_in[8];

  const long SZ  = 139264L * 512;  // 71,303,168 elems (N*D x M)
  const long WSZ = 512L * 512;     // 262,144 elems

  // ws layout (bf16 elems), ~546 MB total with reuse:
  u16* xb   = (u16*)d_ws;        // x bf16; reused as ctx after QKV GEMMs
  u16* wqb  = xb + SZ;
  u16* wkb  = wqb + WSZ;
  u16* wvb  = wkb + WSZ;
  u16* wob  = wvb + WSZ;
  u16* Qb   = wob + WSZ;
  u16* Kb   = Qb + SZ;
  u16* Vb   = Kb + SZ;
  u16* ctxb = xb;                // x_bf16 dead after QKV projections
  float* outpre = (float*)Qb;    // overlays Q+K (dead after attention), 285 MB

  cvt_bf16<<<(int)(SZ / 2048), 256, 0, stream>>>(x, xb, SZ);
  cvt_bf16<<<(int)(WSZ / 2048), 256, 0, stream>>>(Wq, wqb, WSZ);
  cvt_bf16<<<(int)(WSZ / 2048), 256, 0, stream>>>(Wk, wkb, WSZ);
  cvt_bf16<<<(int)(WSZ / 2048), 256, 0, stream>>>(Wv, wvb, WSZ);
  cvt_bf16<<<(int)(WSZ / 2048), 256, 0, stream>>>(Wo, wob, WSZ);

  dim3 g(1088, 4);  // 139264/128 x 512/128
  gemm_bt<0><<<g, 256, 0, stream>>>(xb, wqb, Qb, nullptr, nullptr, nullptr);
  gemm_bt<0><<<g, 256, 0, stream>>>(xb, wkb, Kb, nullptr, nullptr, nullptr);
  gemm_bt<0><<<g, 256, 0, stream>>>(xb, wvb, Vb, nullptr, nullptr, nullptr);

  attn<<<8192, 256, 0, stream>>>(Qb, Kb, Vb, P, ctxb);

  gemm_bt<1><<<g, 256, 0, stream>>>(ctxb, wob, nullptr, outpre, bo, x);

  ln_row<<<34816, 256, 0, stream>>>(outpre, gamma, beta, (float*)d_out);
}

// Round 2
// 1265.657 us; speedup vs baseline: 1.3350x; 1.1362x over previous
//
#include <hip/hip_runtime.h>

typedef unsigned short u16;
typedef unsigned int   u32;
typedef __attribute__((ext_vector_type(8))) short bf16x8;
typedef __attribute__((ext_vector_type(4))) float f32x4;
typedef __attribute__((ext_vector_type(16))) float f32x16;

static __device__ __forceinline__ float bf2f(u16 u) {
  union { u32 i; float f; } v; v.i = ((u32)u) << 16; return v.f;
}
static __device__ __forceinline__ u16 f2bf(float f) {
  union { float f; u32 i; } v; v.f = f;
  u32 u = v.i;
  u32 r = (u + 0x7FFFu + ((u >> 16) & 1u)) >> 16;  // RNE
  return (u16)r;
}

// async global->LDS, 16B per lane; LDS dest is wave-uniform base + lane*16 (linear)
static __device__ __forceinline__ void gload16(const void* g, void* l) {
  __builtin_amdgcn_global_load_lds((const __attribute__((address_space(1))) void*)g,
                                   (__attribute__((address_space(3))) void*)l, 16, 0, 0);
}

// ---------------- f32 -> bf16 conversion, 8 elems/thread ----------------
__global__ __launch_bounds__(256) void cvt_bf16(const float* __restrict__ in,
                                                u16* __restrict__ out, long n) {
  long i = ((long)blockIdx.x * 256 + threadIdx.x) * 8;
  if (i >= n) return;
  float4 a = *(const float4*)(in + i);
  float4 b = *(const float4*)(in + i + 4);
  uint4 o;
  o.x = (u32)f2bf(a.x) | ((u32)f2bf(a.y) << 16);
  o.y = (u32)f2bf(a.z) | ((u32)f2bf(a.w) << 16);
  o.z = (u32)f2bf(b.x) | ((u32)f2bf(b.y) << 16);
  o.w = (u32)f2bf(b.z) | ((u32)f2bf(b.w) << 16);
  *(uint4*)(out + i) = o;
}

// ---------------- full-N GEMM: C[r][c] = sum_k A[r][k] * W[c][k] ----------
// Tile: 128 rows x 512 cols (full N), BK=32, 8 waves (2x4 of 64x128).
// A staged via global_load_lds (linear LDS, source pre-swizzled; ds_read XORs
// the k-chunk with (row>>1)&3 to break the 64B-row-stride bank conflict).
// MODE 0: QKV (matrix = blockIdx.x in {0,1,2}), bf16 out via LDS-repacked
//         uint4 stores. MODE 1: + bias + resid, fused LayerNorm, f32 out.
template <int MODE>
__global__ __launch_bounds__(512, 2) void gemm_fn(
    const u16* __restrict__ A,
    const u16* __restrict__ W0, const u16* __restrict__ W1, const u16* __restrict__ W2,
    u16* __restrict__ C0, u16* __restrict__ C1, u16* __restrict__ C2,
    const float* __restrict__ bias, const float* __restrict__ resid,
    const float* __restrict__ gamma, const float* __restrict__ beta,
    float* __restrict__ outF) {
  __shared__ __align__(16) u16 pool[20480];  // 40 KB: As 8 KB + Ws 32 KB
  u16* As = pool;
  u16* Ws = pool + 4096;
  const int t = threadIdx.x;
  const int lane = t & 63, wave = t >> 6;
  const int wy = wave >> 2, wx = wave & 3;    // wave tile: rows wy*64, cols wx*128
  const int quad = lane >> 4, l15 = lane & 15;
  const long row0 = (long)blockIdx.y * 128;
  const u16* W = (MODE == 1 || blockIdx.x == 0) ? W0 : (blockIdx.x == 1 ? W1 : W2);
  u16* Cb = (blockIdx.x == 0) ? C0 : (blockIdx.x == 1 ? C1 : C2);

  // staging: thread t owns A chunk t (row t>>2, slot t&3) and W chunks i*512+t.
  // source k-segment pre-swizzled by xs=(row>>1)&3 = (t>>3)&3 (same for A and W).
  const int xs = (t >> 3) & 3;
  const u16* aS = A + (row0 + (t >> 2)) * 512 + ((t & 3) ^ xs) * 8;
  const u16* wS = W + (long)(t >> 2) * 512 + ((t & 3) ^ xs) * 8;
  u16* aD = As + t * 8;
  const int xr = (l15 >> 1) & 3;  // read-side XOR: (row>>1)&3 with row=16a+l15

  f32x4 acc[4][8];
#pragma unroll
  for (int i = 0; i < 4; i++)
#pragma unroll
    for (int j = 0; j < 8; j++) acc[i][j] = (f32x4){0.f, 0.f, 0.f, 0.f};

  for (int k0 = 0; k0 < 512; k0 += 32) {
    gload16(aS + k0, aD);
#pragma unroll
    for (int i = 0; i < 4; i++)
      gload16(wS + k0 + (long)i * 65536, Ws + (i * 512 + t) * 8);
    __syncthreads();  // vmcnt(0) drained by compiler before barrier
    bf16x8 af[4];
#pragma unroll
    for (int mt = 0; mt < 4; mt++)
      af[mt] = *(const bf16x8*)(As + (wy * 64 + mt * 16 + l15) * 32 + (quad ^ xr) * 8);
#pragma unroll
    for (int nt = 0; nt < 8; nt++) {
      bf16x8 bv = *(const bf16x8*)(Ws + (wx * 128 + nt * 16 + l15) * 32 + (quad ^ xr) * 8);
#pragma unroll
      for (int mt = 0; mt < 4; mt++)
        acc[mt][nt] = __builtin_amdgcn_mfma_f32_16x16x32_bf16(af[mt], bv,
                                                              acc[mt][nt], 0, 0, 0);
    }
    __syncthreads();
  }

  if (MODE == 0) {
    // repack 32-row strips (both wy) through LDS -> coalesced uint4 stores
#pragma unroll
    for (int mt = 0; mt < 4; mt++) {
#pragma unroll
      for (int nt = 0; nt < 8; nt++)
#pragma unroll
        for (int r = 0; r < 4; r++)
          pool[(wy * 16 + quad * 4 + r) * 512 + wx * 128 + nt * 16 + l15] =
              f2bf(acc[mt][nt][r]);
      __syncthreads();
#pragma unroll
      for (int i = 0; i < 4; i++) {
        const int off = i * 512 + t;          // 16B units in 32x512 strip
        uint4 v = ((const uint4*)pool)[off];
        const int sr = off >> 6, sc8 = off & 63;
        const long gr = row0 + (sr >> 4) * 64 + mt * 16 + (sr & 15);
        *(uint4*)(Cb + gr * 512 + sc8 * 8) = v;
      }
      __syncthreads();
    }
  } else {
    // fused epilogue: + bias + resid, LayerNorm over the full 512-row, f32 out
    float gv[8], bt[8], bias8[8];
#pragma unroll
    for (int e = 0; e < 8; e++) {
      gv[e] = gamma[lane * 8 + e];
      bt[e] = beta[lane * 8 + e];
    }
#pragma unroll
    for (int nt = 0; nt < 8; nt++) bias8[nt] = bias[wx * 128 + nt * 16 + l15];
    float* Sf = (float*)pool;  // 16 x 512 f32 strip (32 KB)
#pragma unroll
    for (int mt = 0; mt < 4; mt++) {
      for (int wys = 0; wys < 2; wys++) {
        if (wy == wys) {
#pragma unroll
          for (int nt = 0; nt < 8; nt++) {
            const int col = wx * 128 + nt * 16 + l15;
#pragma unroll
            for (int r = 0; r < 4; r++) {
              const long grow = row0 + wys * 64 + mt * 16 + quad * 4 + r;
              Sf[(quad * 4 + r) * 512 + col] =
                  acc[mt][nt][r] + bias8[nt] + resid[grow * 512 + col];
            }
          }
        }
        __syncthreads();
#pragma unroll
        for (int rr = 0; rr < 2; rr++) {
          const int lr = wave * 2 + rr;
          const float* rp = Sf + lr * 512 + lane * 8;
          float4 a = *(const float4*)(rp);
          float4 b = *(const float4*)(rp + 4);
          float s  = a.x + a.y + a.z + a.w + b.x + b.y + b.z + b.w;
          float sq = a.x*a.x + a.y*a.y + a.z*a.z + a.w*a.w +
                     b.x*b.x + b.y*b.y + b.z*b.z + b.w*b.w;
#pragma unroll
          for (int off = 1; off < 64; off <<= 1) {
            s  += __shfl_xor(s, off);
            sq += __shfl_xor(sq, off);
          }
          const float mean = s * (1.f / 512.f);
          const float var  = sq * (1.f / 512.f) - mean * mean;
          const float rstd = rsqrtf(var + 1e-5f);
          float4 o0, o1;
          o0.x = (a.x - mean) * rstd * gv[0] + bt[0];
          o0.y = (a.y - mean) * rstd * gv[1] + bt[1];
          o0.z = (a.z - mean) * rstd * gv[2] + bt[2];
          o0.w = (a.w - mean) * rstd * gv[3] + bt[3];
          o1.x = (b.x - mean) * rstd * gv[4] + bt[4];
          o1.y = (b.y - mean) * rstd * gv[5] + bt[5];
          o1.z = (b.z - mean) * rstd * gv[6] + bt[6];
          o1.w = (b.w - mean) * rstd * gv[7] + bt[7];
          const long grow = row0 + wys * 64 + mt * 16 + lr;
          float* op = outF + grow * 512 + lane * 8;
          *(float4*)op = o0;
          *(float4*)(op + 4) = o1;
        }
        __syncthreads();
      }
    }
  }
}

// ---------------- attention (MFMA): one block per sample n ----------------
__global__ __launch_bounds__(256) void attn(
    const u16* __restrict__ Q, const u16* __restrict__ K, const u16* __restrict__ V,
    const float* __restrict__ P, u16* __restrict__ CTX) {
  __shared__ __align__(16) u16 vs[17 * 512];
  __shared__ float Ps[17 * 17];
  const int t = threadIdx.x;
  const long base = (long)blockIdx.x * (17 * 512);
  for (int c = t; c < 1088; c += 256)
    ((uint4*)vs)[c] = *(const uint4*)(V + base + c * 8);
  for (int c = t; c < 289; c += 256) Ps[c] = P[c];
  __syncthreads();

  const int lane = t & 63, wave = t >> 6;
  const int l31 = lane & 31, hi = lane >> 5;
  const int i17 = l31 < 17 ? l31 : 16;

  for (int hh = 0; hh < 2; hh++) {
    const int h = wave + hh * 4;
    const u16* kbase = K + base + (long)l31 * 512 + h * 64 + hi * 8;
    const u16* qbase = Q + base + (long)l31 * 512 + h * 64 + hi * 8;

    f32x16 acc;
#pragma unroll
    for (int r = 0; r < 16; r++) acc[r] = 0.f;
#pragma unroll
    for (int ks = 0; ks < 4; ks++) {
      bf16x8 ka = *(const bf16x8*)(kbase + ks * 16);
      bf16x8 qb = *(const bf16x8*)(qbase + ks * 16);
      acc = __builtin_amdgcn_mfma_f32_32x32x16_bf16(ka, qb, acc, 0, 0, 0);
    }

    float tt[9], xx[9];
#pragma unroll
    for (int r = 0; r < 9; r++) {
      const int jown = (r & 3) + 8 * (r >> 2);
      int j = jown + 4 * hi;
      if (j > 16) j = 16;
      tt[r] = acc[r] * 0.125f + Ps[i17 * 17 + j];
    }
#pragma unroll
    for (int r = 0; r < 9; r++) xx[r] = __shfl_xor(tt[r], 32, 64);

    float s[17];
#pragma unroll
    for (int r = 0; r < 4; r++) {
      s[r]      = hi ? xx[r] : tt[r];
      s[r + 4]  = hi ? tt[r] : xx[r];
      s[r + 8]  = hi ? xx[r + 4] : tt[r + 4];
      s[r + 12] = hi ? tt[r + 4] : xx[r + 4];
    }
    s[16] = hi ? xx[8] : tt[8];

    float mx = s[0];
#pragma unroll
    for (int j = 1; j < 17; j++) mx = fmaxf(mx, s[j]);
    float p[17], sum = 0.f;
#pragma unroll
    for (int j = 0; j < 17; j++) { p[j] = __expf(s[j] - mx); sum += p[j]; }
    const float inv = 1.f / sum;

    bf16x8 pa0, pa1;
#pragma unroll
    for (int e = 0; e < 8; e++) {
      const float v0 = (hi ? p[8 + e] : p[e]) * inv;
      pa0[e] = (short)f2bf(v0);
      pa1[e] = 0;
    }
    if (hi == 0) pa1[0] = (short)f2bf(p[16] * inv);

#pragma unroll
    for (int tile = 0; tile < 2; tile++) {
      const int c = h * 64 + tile * 32 + l31;
      bf16x8 vb0, vb1;
#pragma unroll
      for (int e = 0; e < 8; e++) {
        vb0[e] = (short)vs[(hi * 8 + e) * 512 + c];
        vb1[e] = 0;
      }
      if (hi == 0) vb1[0] = (short)vs[16 * 512 + c];

      f32x16 o;
#pragma unroll
      for (int r = 0; r < 16; r++) o[r] = 0.f;
      o = __builtin_amdgcn_mfma_f32_32x32x16_bf16(pa0, vb0, o, 0, 0, 0);
      o = __builtin_amdgcn_mfma_f32_32x32x16_bf16(pa1, vb1, o, 0, 0, 0);

      u16* cp = CTX + base + c;
#pragma unroll
      for (int r = 0; r < 16; r++) {
        const int i = (r & 3) + 8 * (r >> 2) + 4 * hi;
        if (i < 17) cp[(long)i * 512] = f2bf(o[r]);
      }
    }
  }
}

extern "C" void kernel_launch(void* const* d_in, const int* in_sizes, int n_in,
                              void* d_out, int out_size, void* d_ws, size_t ws_size,
                              hipStream_t stream) {
  const float* x     = (const float*)d_in[0];
  const float* P     = (const float*)d_in[1];
  const float* Wq    = (const float*)d_in[2];
  const float* Wk    = (const float*)d_in[3];
  const float* Wv    = (const float*)d_in[4];
  const float* Wo    = (const float*)d_in[5];
  const float* bo    = (const float*)d_in[6];
  const float* gamma = (const float*)d_in[7];
  const float* beta  = (const float*)d_in[8];

  const long SZ  = 139264L * 512;
  const long WSZ = 512L * 512;

  u16* xb   = (u16*)d_ws;        // x bf16; reused as ctx after attention
  u16* wqb  = xb + SZ;
  u16* wkb  = wqb + WSZ;
  u16* wvb  = wkb + WSZ;
  u16* wob  = wvb + WSZ;
  u16* Qb   = wob + WSZ;
  u16* Kb   = Qb + SZ;
  u16* Vb   = Kb + SZ;
  u16* ctxb = xb;                // x_bf16 dead after QKV projections

  cvt_bf16<<<(int)(SZ / 2048), 256, 0, stream>>>(x, xb, SZ);
  cvt_bf16<<<(int)(WSZ / 2048), 256, 0, stream>>>(Wq, wqb, WSZ);
  cvt_bf16<<<(int)(WSZ / 2048), 256, 0, stream>>>(Wk, wkb, WSZ);
  cvt_bf16<<<(int)(WSZ / 2048), 256, 0, stream>>>(Wv, wvb, WSZ);
  cvt_bf16<<<(int)(WSZ / 2048), 256, 0, stream>>>(Wo, wob, WSZ);

  // fused QKV: blockIdx.x selects matrix (x fastest -> the 3 matrices sweep
  // the same A rows together; L3/L2 dedup the re-reads)
  gemm_fn<0><<<dim3(3, 1088), 512, 0, stream>>>(
      xb, wqb, wkb, wvb, Qb, Kb, Vb, nullptr, nullptr, nullptr, nullptr, nullptr);

  attn<<<8192, 256, 0, stream>>>(Qb, Kb, Vb, P, ctxb);

  // out = ctx @ Wo^T + bo + x, then LayerNorm -- all fused, writes final out
  gemm_fn<1><<<dim3(1, 1088), 512, 0, stream>>>(
      ctxb, wob, nullptr, nullptr, nullptr, nullptr, nullptr,
      bo, x, gamma, beta, (float*)d_out);
}

// Round 3
// 1151.243 us; speedup vs baseline: 1.4677x; 1.0994x over previous
//
#include <hip/hip_runtime.h>

typedef unsigned short u16;
typedef unsigned int   u32;
typedef __attribute__((ext_vector_type(8))) short bf16x8;
typedef __attribute__((ext_vector_type(4))) float f32x4;
typedef __attribute__((ext_vector_type(16))) float f32x16;

static __device__ __forceinline__ float bf2f(u16 u) {
  union { u32 i; float f; } v; v.i = ((u32)u) << 16; return v.f;
}
static __device__ __forceinline__ u16 f2bf(float f) {
  union { float f; u32 i; } v; v.f = f;
  u32 u = v.i;
  u32 r = (u + 0x7FFFu + ((u >> 16) & 1u)) >> 16;  // RNE
  return (u16)r;
}

// async global->LDS, 16B per lane; LDS dest is wave-uniform base + lane*16 (linear)
static __device__ __forceinline__ void gload16(const void* g, void* l) {
  __builtin_amdgcn_global_load_lds((const __attribute__((address_space(1))) void*)g,
                                   (__attribute__((address_space(3))) void*)l, 16, 0, 0);
}

// ---------------- f32 -> bf16 conversion, 8 elems/thread ----------------
__global__ __launch_bounds__(256) void cvt_bf16(const float* __restrict__ in,
                                                u16* __restrict__ out, long n) {
  long i = ((long)blockIdx.x * 256 + threadIdx.x) * 8;
  if (i >= n) return;
  float4 a = *(const float4*)(in + i);
  float4 b = *(const float4*)(in + i + 4);
  uint4 o;
  o.x = (u32)f2bf(a.x) | ((u32)f2bf(a.y) << 16);
  o.y = (u32)f2bf(a.z) | ((u32)f2bf(a.w) << 16);
  o.z = (u32)f2bf(b.x) | ((u32)f2bf(b.y) << 16);
  o.w = (u32)f2bf(b.z) | ((u32)f2bf(b.w) << 16);
  *(uint4*)(out + i) = o;
}

// ---------------- full-N GEMM: C[r][c] = sum_k A[r][k] * W[c][k] ----------
// Tile 128 rows x 512 cols, 8 waves (2x4 of 64x128), compute BK=32.
// Double-buffered staging via global_load_lds, 2-phase pipeline (stage t+1
// before compute t, ONE barrier per k-step). A staged at 64-col granularity
// (full 128B lines -> no half-line refetch); XOR-swizzled sources, linear LDS.
// MODE 0: QKV fused (XCD-coherent swizzle: the 3 matrices of a row-tile map
//         to dispatch ids differing by 8 -> same XCD L2 under round-robin).
// MODE 1: + bias + resid, fused LayerNorm, f32 out.
template <int MODE>
__global__ __launch_bounds__(512, 2) void gemm_fn(
    const u16* __restrict__ A,
    const u16* __restrict__ W0, const u16* __restrict__ W1, const u16* __restrict__ W2,
    u16* __restrict__ C0, u16* __restrict__ C1, u16* __restrict__ C2,
    const float* __restrict__ bias, const float* __restrict__ resid,
    const float* __restrict__ gamma, const float* __restrict__ beta,
    float* __restrict__ outF) {
  __shared__ __align__(16) u16 pool[49152];  // 96 KB
  u16* const Ab0 = pool;               // A pair buffers: 128 rows x 64 cols
  u16* const Ab1 = pool + 8192;
  u16* const Wb0 = pool + 16384;       // W step buffers: 512 rows x 32 cols
  u16* const Wb1 = pool + 32768;
  const int t = threadIdx.x;
  const int lane = t & 63, wave = t >> 6;
  const int wy = wave >> 2, wx = wave & 3;
  const int quad = lane >> 4, l15 = lane & 15;

  int mat, rt;
  if (MODE == 0) {
    const int f = blockIdx.x, g = f / 24, w = f % 24;
    mat = w >> 3;            // 0..2 (matrix)
    rt  = g * 8 + (w & 7);   // row-tile; trio {mat} shares XCD (ids differ by 8)
  } else {
    mat = 0; rt = blockIdx.x;
  }
  const long row0 = (long)rt * 128;
  const u16* W = (MODE == 1 || mat == 0) ? W0 : (mat == 1 ? W1 : W2);
  u16* Cb = (mat == 0) ? C0 : (mat == 1 ? C1 : C2);

  // A staging: thread owns chunks c = t, t+512 (row = c>>3, slot = c&7),
  // source slot pre-XOR'd by (row&7); pair stride = 64 cols.
  const int ar0 = t >> 3, as0 = t & 7;
  const u16* aSrc0 = A + (row0 + ar0) * 512 + (as0 ^ (ar0 & 7)) * 8;
  const u16* aSrc1 = A + (row0 + ar0 + 64) * 512 + (as0 ^ ((ar0 + 64) & 7)) * 8;
  // W staging: chunks c = t + i*512 (row = c>>2, seg = c&3), XOR (row>>1)&3.
  const u16* wSrc0, *wSrc1, *wSrc2, *wSrc3;
  {
    const int r0 = t >> 2, sg = t & 3;
    wSrc0 = W + (long)(r0      ) * 512 + (sg ^ (((r0      ) >> 1) & 3)) * 8;
    wSrc1 = W + (long)(r0 + 128) * 512 + (sg ^ (((r0 + 128) >> 1) & 3)) * 8;
    wSrc2 = W + (long)(r0 + 256) * 512 + (sg ^ (((r0 + 256) >> 1) & 3)) * 8;
    wSrc3 = W + (long)(r0 + 384) * 512 + (sg ^ (((r0 + 384) >> 1) & 3)) * 8;
  }

  f32x4 acc[4][8];
#pragma unroll
  for (int i = 0; i < 4; i++)
#pragma unroll
    for (int j = 0; j < 8; j++) acc[i][j] = (f32x4){0.f, 0.f, 0.f, 0.f};

  // prologue: A pair 0 -> Ab0, W step 0 -> Wb0
  gload16(aSrc0, Ab0 + t * 8);
  gload16(aSrc1, Ab0 + (t + 512) * 8);
  gload16(wSrc0, Wb0 + t * 8);
  gload16(wSrc1, Wb0 + (t + 512) * 8);
  gload16(wSrc2, Wb0 + (t + 1024) * 8);
  gload16(wSrc3, Wb0 + (t + 1536) * 8);
  __syncthreads();

#pragma unroll
  for (int tt = 0; tt < 16; ++tt) {
    // stage next A pair (every other step) and next W step into the idle bufs
    if ((tt & 1) == 0 && tt < 14) {
      const int p = (tt >> 1) + 1;
      u16* const d = (p & 1) ? Ab1 : Ab0;
      gload16(aSrc0 + p * 64, d + t * 8);
      gload16(aSrc1 + p * 64, d + (t + 512) * 8);
    }
    if (tt < 15) {
      u16* const d = ((tt + 1) & 1) ? Wb1 : Wb0;
      const int kn = (tt + 1) * 32;
      gload16(wSrc0 + kn, d + t * 8);
      gload16(wSrc1 + kn, d + (t + 512) * 8);
      gload16(wSrc2 + kn, d + (t + 1024) * 8);
      gload16(wSrc3 + kn, d + (t + 1536) * 8);
    }
    // compute current step
    const u16* const Ar = ((tt >> 1) & 1) ? Ab1 : Ab0;
    const u16* const Wr = (tt & 1) ? Wb1 : Wb0;
    const int kk = tt & 1;
    bf16x8 af[4];
#pragma unroll
    for (int mt = 0; mt < 4; mt++) {
      const int row = wy * 64 + mt * 16 + l15;
      af[mt] = *(const bf16x8*)(Ar + row * 64 + ((((kk << 2) | quad) ^ (l15 & 7)) * 8));
    }
#pragma unroll
    for (int nt = 0; nt < 8; nt++) {
      const int row = wx * 128 + nt * 16 + l15;
      bf16x8 bv = *(const bf16x8*)(Wr + row * 32 + ((quad ^ ((l15 >> 1) & 3)) * 8));
#pragma unroll
      for (int mt = 0; mt < 4; mt++)
        acc[mt][nt] = __builtin_amdgcn_mfma_f32_16x16x32_bf16(af[mt], bv,
                                                              acc[mt][nt], 0, 0, 0);
    }
    __syncthreads();
  }

  if (MODE == 0) {
    // repack 32-row strips through LDS -> coalesced uint4 stores
#pragma unroll
    for (int mt = 0; mt < 4; mt++) {
#pragma unroll
      for (int nt = 0; nt < 8; nt++)
#pragma unroll
        for (int r = 0; r < 4; r++)
          pool[(wy * 16 + quad * 4 + r) * 512 + wx * 128 + nt * 16 + l15] =
              f2bf(acc[mt][nt][r]);
      __syncthreads();
#pragma unroll
      for (int i = 0; i < 4; i++) {
        const int off = i * 512 + t;          // 16B units in 32x512 strip
        uint4 v = ((const uint4*)pool)[off];
        const int sr = off >> 6, sc8 = off & 63;
        const long gr = row0 + (sr >> 4) * 64 + mt * 16 + (sr & 15);
        *(uint4*)(Cb + gr * 512 + sc8 * 8) = v;
      }
      __syncthreads();
    }
  } else {
    // fused epilogue: + bias + resid, LayerNorm over the full 512-row, f32 out
    float gv[8], bt[8], bias8[8];
#pragma unroll
    for (int e = 0; e < 8; e++) {
      gv[e] = gamma[lane * 8 + e];
      bt[e] = beta[lane * 8 + e];
    }
#pragma unroll
    for (int nt = 0; nt < 8; nt++) bias8[nt] = bias[wx * 128 + nt * 16 + l15];
    float* Sf = (float*)pool;  // 16 x 512 f32 strip (32 KB)
#pragma unroll
    for (int mt = 0; mt < 4; mt++) {
      for (int wys = 0; wys < 2; wys++) {
        if (wy == wys) {
#pragma unroll
          for (int nt = 0; nt < 8; nt++) {
            const int col = wx * 128 + nt * 16 + l15;
#pragma unroll
            for (int r = 0; r < 4; r++) {
              const long grow = row0 + wys * 64 + mt * 16 + quad * 4 + r;
              Sf[(quad * 4 + r) * 512 + col] =
                  acc[mt][nt][r] + bias8[nt] + resid[grow * 512 + col];
            }
          }
        }
        __syncthreads();
#pragma unroll
        for (int rr = 0; rr < 2; rr++) {
          const int lr = wave * 2 + rr;
          const float* rp = Sf + lr * 512 + lane * 8;
          float4 a = *(const float4*)(rp);
          float4 b = *(const float4*)(rp + 4);
          float s  = a.x + a.y + a.z + a.w + b.x + b.y + b.z + b.w;
          float sq = a.x*a.x + a.y*a.y + a.z*a.z + a.w*a.w +
                     b.x*b.x + b.y*b.y + b.z*b.z + b.w*b.w;
#pragma unroll
          for (int off = 1; off < 64; off <<= 1) {
            s  += __shfl_xor(s, off);
            sq += __shfl_xor(sq, off);
          }
          const float mean = s * (1.f / 512.f);
          const float var  = sq * (1.f / 512.f) - mean * mean;
          const float rstd = rsqrtf(var + 1e-5f);
          float4 o0, o1;
          o0.x = (a.x - mean) * rstd * gv[0] + bt[0];
          o0.y = (a.y - mean) * rstd * gv[1] + bt[1];
          o0.z = (a.z - mean) * rstd * gv[2] + bt[2];
          o0.w = (a.w - mean) * rstd * gv[3] + bt[3];
          o1.x = (b.x - mean) * rstd * gv[4] + bt[4];
          o1.y = (b.y - mean) * rstd * gv[5] + bt[5];
          o1.z = (b.z - mean) * rstd * gv[6] + bt[6];
          o1.w = (b.w - mean) * rstd * gv[7] + bt[7];
          const long grow = row0 + wys * 64 + mt * 16 + lr;
          float* op = outF + grow * 512 + lane * 8;
          *(float4*)op = o0;
          *(float4*)(op + 4) = o1;
        }
        __syncthreads();
      }
    }
  }
}

// ---------------- attention (MFMA): one block per sample n ----------------
__global__ __launch_bounds__(256) void attn(
    const u16* __restrict__ Q, const u16* __restrict__ K, const u16* __restrict__ V,
    const float* __restrict__ P, u16* __restrict__ CTX) {
  __shared__ __align__(16) u16 vs[17 * 512];
  __shared__ float Ps[17 * 17];
  const int t = threadIdx.x;
  const long base = (long)blockIdx.x * (17 * 512);
  for (int c = t; c < 1088; c += 256)
    ((uint4*)vs)[c] = *(const uint4*)(V + base + c * 8);
  for (int c = t; c < 289; c += 256) Ps[c] = P[c];
  __syncthreads();

  const int lane = t & 63, wave = t >> 6;
  const int l31 = lane & 31, hi = lane >> 5;
  const int i17 = l31 < 17 ? l31 : 16;

  for (int hh = 0; hh < 2; hh++) {
    const int h = wave + hh * 4;
    const u16* kbase = K + base + (long)l31 * 512 + h * 64 + hi * 8;
    const u16* qbase = Q + base + (long)l31 * 512 + h * 64 + hi * 8;

    f32x16 acc;
#pragma unroll
    for (int r = 0; r < 16; r++) acc[r] = 0.f;
#pragma unroll
    for (int ks = 0; ks < 4; ks++) {
      bf16x8 ka = *(const bf16x8*)(kbase + ks * 16);
      bf16x8 qb = *(const bf16x8*)(qbase + ks * 16);
      acc = __builtin_amdgcn_mfma_f32_32x32x16_bf16(ka, qb, acc, 0, 0, 0);
    }

    float tt[9], xx[9];
#pragma unroll
    for (int r = 0; r < 9; r++) {
      const int jown = (r & 3) + 8 * (r >> 2);
      int j = jown + 4 * hi;
      if (j > 16) j = 16;
      tt[r] = acc[r] * 0.125f + Ps[i17 * 17 + j];
    }
#pragma unroll
    for (int r = 0; r < 9; r++) xx[r] = __shfl_xor(tt[r], 32, 64);

    float s[17];
#pragma unroll
    for (int r = 0; r < 4; r++) {
      s[r]      = hi ? xx[r] : tt[r];
      s[r + 4]  = hi ? tt[r] : xx[r];
      s[r + 8]  = hi ? xx[r + 4] : tt[r + 4];
      s[r + 12] = hi ? tt[r + 4] : xx[r + 4];
    }
    s[16] = hi ? xx[8] : tt[8];

    float mx = s[0];
#pragma unroll
    for (int j = 1; j < 17; j++) mx = fmaxf(mx, s[j]);
    float p[17], sum = 0.f;
#pragma unroll
    for (int j = 0; j < 17; j++) { p[j] = __expf(s[j] - mx); sum += p[j]; }
    const float inv = 1.f / sum;

    bf16x8 pa0, pa1;
#pragma unroll
    for (int e = 0; e < 8; e++) {
      const float v0 = (hi ? p[8 + e] : p[e]) * inv;
      pa0[e] = (short)f2bf(v0);
      pa1[e] = 0;
    }
    if (hi == 0) pa1[0] = (short)f2bf(p[16] * inv);

#pragma unroll
    for (int tile = 0; tile < 2; tile++) {
      const int c = h * 64 + tile * 32 + l31;
      bf16x8 vb0, vb1;
#pragma unroll
      for (int e = 0; e < 8; e++) {
        vb0[e] = (short)vs[(hi * 8 + e) * 512 + c];
        vb1[e] = 0;
      }
      if (hi == 0) vb1[0] = (short)vs[16 * 512 + c];

      f32x16 o;
#pragma unroll
      for (int r = 0; r < 16; r++) o[r] = 0.f;
      o = __builtin_amdgcn_mfma_f32_32x32x16_bf16(pa0, vb0, o, 0, 0, 0);
      o = __builtin_amdgcn_mfma_f32_32x32x16_bf16(pa1, vb1, o, 0, 0, 0);

      u16* cp = CTX + base + c;
#pragma unroll
      for (int r = 0; r < 16; r++) {
        const int i = (r & 3) + 8 * (r >> 2) + 4 * hi;
        if (i < 17) cp[(long)i * 512] = f2bf(o[r]);
      }
    }
  }
}

extern "C" void kernel_launch(void* const* d_in, const int* in_sizes, int n_in,
                              void* d_out, int out_size, void* d_ws, size_t ws_size,
                              hipStream_t stream) {
  const float* x     = (const float*)d_in[0];
  const float* P     = (const float*)d_in[1];
  const float* Wq    = (const float*)d_in[2];
  const float* Wk    = (const float*)d_in[3];
  const float* Wv    = (const float*)d_in[4];
  const float* Wo    = (const float*)d_in[5];
  const float* bo    = (const float*)d_in[6];
  const float* gamma = (const float*)d_in[7];
  const float* beta  = (const float*)d_in[8];

  const long SZ  = 139264L * 512;
  const long WSZ = 512L * 512;

  u16* xb   = (u16*)d_ws;        // x bf16; reused as ctx after attention
  u16* wqb  = xb + SZ;
  u16* wkb  = wqb + WSZ;
  u16* wvb  = wkb + WSZ;
  u16* wob  = wvb + WSZ;
  u16* Qb   = wob + WSZ;
  u16* Kb   = Qb + SZ;
  u16* Vb   = Kb + SZ;
  u16* ctxb = xb;                // x_bf16 dead after QKV projections

  cvt_bf16<<<(int)(SZ / 2048), 256, 0, stream>>>(x, xb, SZ);
  cvt_bf16<<<(int)(WSZ / 2048), 256, 0, stream>>>(Wq, wqb, WSZ);
  cvt_bf16<<<(int)(WSZ / 2048), 256, 0, stream>>>(Wk, wkb, WSZ);
  cvt_bf16<<<(int)(WSZ / 2048), 256, 0, stream>>>(Wv, wvb, WSZ);
  cvt_bf16<<<(int)(WSZ / 2048), 256, 0, stream>>>(Wo, wob, WSZ);

  // fused QKV, 1D grid with XCD-coherent swizzle (see kernel)
  gemm_fn<0><<<3264, 512, 0, stream>>>(
      xb, wqb, wkb, wvb, Qb, Kb, Vb, nullptr, nullptr, nullptr, nullptr, nullptr);

  attn<<<8192, 256, 0, stream>>>(Qb, Kb, Vb, P, ctxb);

  // out = ctx @ Wo^T + bo + x, then LayerNorm -- fused, writes final out
  gemm_fn<1><<<1088, 512, 0, stream>>>(
      ctxb, wob, nullptr, nullptr, nullptr, nullptr, nullptr,
      bo, x, gamma, beta, (float*)d_out);
}